// Round 13
// baseline (3195.599 us; speedup 1.0000x reference)
//
#include <hip/hip_runtime.h>
#include <hip/hip_bf16.h>

// B=2048, T=80, V=80, E=8, H=256. 2-layer LSTM + dense(last step).
// v7 = v6 + wbuf wrap fix: v6's weight double-buffer refill was guarded by
// kk<7 with the initial load hoisted out of the t-loop -> at t>=1, kk=0 used
// group-6 weights (absmax 1.6e-2). Refill now wraps: ng=(kk+1)&7, so kk=7
// prefetches group 0 for the next step (weights t-invariant).
// Geometry: M=32 rows/block, 64 blocks x 512 thr, launch_bounds(512,2)
// (only config measured to give >64 VGPRs). za-hoisting chunked by ws_size.

#define BB 2048
#define TT 80
#define VV 80
#define HH 256

typedef _Float16 half8 __attribute__((ext_vector_type(8)));
typedef _Float16 half4v __attribute__((ext_vector_type(4)));
typedef float f32x4 __attribute__((ext_vector_type(4)));

__device__ __forceinline__ float sigf(float x) { return 1.0f / (1.0f + __expf(-x)); }
__device__ __forceinline__ float tanhfast(float x) { return 2.0f * sigf(2.0f * x) - 1.0f; }

// LDS h-tile row: 512B, XOR-swizzled 16B slots. Buffers hold 32 rows (16KB).
__device__ __forceinline__ int swz(int row, int kbyte) {
    return row * 512 + (kbyte ^ ((row & 7) << 4));
}

// ---------------- prep ----------------
__global__ void prep_table(const float* __restrict__ emb, const float* __restrict__ W1,
                           const float* __restrict__ b1, float* __restrict__ tbl) {
    int v = blockIdx.x, d = threadIdx.x;
    float4 s;
    s.x = b1[d]; s.y = b1[256 + d]; s.z = b1[512 + d] + 1.0f; s.w = b1[768 + d];
    #pragma unroll
    for (int e = 0; e < 8; ++e) {
        float xv = emb[v * 8 + e];
        const float* wr = W1 + (size_t)e * 1024;
        s.x = fmaf(xv, wr[d], s.x);
        s.y = fmaf(xv, wr[256 + d], s.y);
        s.z = fmaf(xv, wr[512 + d], s.z);
        s.w = fmaf(xv, wr[768 + d], s.w);
    }
    ((float4*)tbl)[v * 256 + d] = s;
}

// v6/v7 stream (8 waves x 32 dims): half8 idx = (((w*8+kk)*2+j)*4+g)*64 + l
//   col = g*256 + w*32 + j*16 + (l&15), krow = base + kk*32 + (l>>4)*8 + e
__global__ void prep_w1_v6(const float* __restrict__ W1, _Float16* __restrict__ Wf) {
    int tid = blockIdx.x * 256 + threadIdx.x;              // 32768
    int l = tid & 63, g = (tid >> 6) & 3, j = (tid >> 8) & 1;
    int kk = (tid >> 9) & 7, w = (tid >> 12) & 7;
    int col = g * 256 + w * 32 + j * 16 + (l & 15);
    size_t base = ((size_t)((((w * 8 + kk) * 2 + j) * 4 + g)) * 64 + l) * 8;
    #pragma unroll
    for (int e = 0; e < 8; ++e) {
        int krow = 8 + kk * 32 + (l >> 4) * 8 + e;         // skip E rows
        Wf[base + e] = (_Float16)W1[(size_t)krow * 1024 + col];
    }
}
__global__ void prep_w2h_v6(const float* __restrict__ W2, _Float16* __restrict__ Wf) {
    int tid = blockIdx.x * 256 + threadIdx.x;              // 32768
    int l = tid & 63, g = (tid >> 6) & 3, j = (tid >> 8) & 1;
    int kk = (tid >> 9) & 7, w = (tid >> 12) & 7;
    int col = g * 256 + w * 32 + j * 16 + (l & 15);
    size_t base = ((size_t)((((w * 8 + kk) * 2 + j) * 4 + g)) * 64 + l) * 8;
    #pragma unroll
    for (int e = 0; e < 8; ++e) {
        int krow = 256 + kk * 32 + (l >> 4) * 8 + e;       // h2 half
        Wf[base + e] = (_Float16)W2[(size_t)krow * 1024 + col];
    }
}
// za_gemm keeps the 16-wave M=16 layout.
__global__ void prep_w2za_v2(const float* __restrict__ W2, _Float16* __restrict__ Wf) {
    int tid = blockIdx.x * 256 + threadIdx.x;              // 32768
    int l = tid & 63, g = (tid >> 6) & 3, kk = (tid >> 8) & 7, w = (tid >> 11) & 15;
    int col = g * 256 + w * 16 + (l & 15);
    size_t base = ((size_t)((w * 8 + kk) * 4 + g) * 64 + l) * 8;
    #pragma unroll
    for (int e = 0; e < 8; ++e) {
        int krow = kk * 32 + (l >> 4) * 8 + e;             // h1 half
        Wf[base + e] = (_Float16)W2[(size_t)krow * 1024 + col];
    }
}
// Old (R6) layout for fallback lstm2 (K=512, 1 MiB).
__global__ void prep_w2_old(const float* __restrict__ W2, _Float16* __restrict__ Wf) {
    int tid = blockIdx.x * 256 + threadIdx.x;              // 65536
    int l = tid & 63, kk = (tid >> 6) & 7, j = (tid >> 9) & 1;
    int g = (tid >> 10) & 3, s = (tid >> 12) & 1, w = tid >> 13;
    int col = g * 256 + w * 32 + j * 16 + (l & 15);
    size_t base = ((size_t)((w * 16 + s * 8 + g * 2 + j) * 8 + kk) * 64 + l) * 8;
    #pragma unroll
    for (int e = 0; e < 8; ++e) {
        int krow = (1 - s) * 256 + kk * 32 + (l >> 4) * 8 + e;
        Wf[base + e] = (_Float16)W2[(size_t)krow * 1024 + col];
    }
}

// ---------------- phase 1: 64 blocks x 512 thr, M=32 ----------------
__global__ __launch_bounds__(512, 2) void lstm1_v7(
    const int* __restrict__ feats, const float* __restrict__ tbl,
    const _Float16* __restrict__ Wf, _Float16* __restrict__ h1out)
{
    __shared__ char hb0[16384], hb1[16384];
    __shared__ int f_lds[32 * TT];
    const int tid = threadIdx.x, l = tid & 63, w = tid >> 6;
    const int row_a = l & 15, chunk = l >> 4;
    const int dim0 = w * 32 + (l & 15);
    const int crow0 = (l >> 4) * 4;
    const int brow = blockIdx.x * 32;

    for (int i = tid; i < 4096; i += 512) ((float*)hb0)[i] = 0.f;
    for (int i = tid; i < 32 * TT; i += 512)
        f_lds[i] = feats[(size_t)(brow + i / TT) * TT + (i % TT)];
    float c[2][2][4] = {};
    const float4* tblv = (const float4*)tbl;
    const half8* wp = (const half8*)Wf + (size_t)w * 4096;

    half8 wbuf[2][8];
    #pragma unroll
    for (int jg = 0; jg < 8; ++jg) wbuf[0][jg] = wp[jg * 64 + l];
    __syncthreads();

    for (int t = 0; t < TT; ++t) {
        char* cur = (t & 1) ? hb1 : hb0;
        char* nxt = (t & 1) ? hb0 : hb1;

        // coalesced h(t-1) -> global (cur holds it; fills post-barrier gap)
        if (t > 0) {
            #pragma unroll
            for (int p = 0; p < 2; ++p) {
                int i = p * 512 + tid, r = i >> 5, c16 = i & 31;
                *(half8*)(h1out + ((size_t)(t - 1) * BB + brow + r) * HH + c16 * 8) =
                    *(const half8*)(cur + swz(r, c16 * 16));
            }
        }

        f32x4 acc[2][2][4];
        #pragma unroll
        for (int rt = 0; rt < 2; ++rt)
            #pragma unroll
            for (int j = 0; j < 2; ++j)
                #pragma unroll
                for (int g = 0; g < 4; ++g) acc[rt][j][g] = (f32x4){0.f, 0.f, 0.f, 0.f};

        #pragma unroll
        for (int kk = 0; kk < 8; ++kk) {
            const int cb = kk & 1;
            const int ng = (kk + 1) & 7;     // WRAP: kk=7 reloads group 0
            #pragma unroll
            for (int jg = 0; jg < 8; ++jg)
                wbuf[cb ^ 1][jg] = wp[(size_t)(ng * 8 + jg) * 64 + l];
            half8 a0 = *(const half8*)(cur + swz(row_a,      kk * 64 + chunk * 16));
            half8 a1 = *(const half8*)(cur + swz(row_a + 16, kk * 64 + chunk * 16));
            #pragma unroll
            for (int j = 0; j < 2; ++j)
                #pragma unroll
                for (int g = 0; g < 4; ++g) {
                    acc[0][j][g] = __builtin_amdgcn_mfma_f32_16x16x32_f16(
                        a0, wbuf[cb][j * 4 + g], acc[0][j][g], 0, 0, 0);
                    acc[1][j][g] = __builtin_amdgcn_mfma_f32_16x16x32_f16(
                        a1, wbuf[cb][j * 4 + g], acc[1][j][g], 0, 0, 0);
                }
        }

        #pragma unroll
        for (int rt = 0; rt < 2; ++rt) {
            float4 tb[2][4];
            #pragma unroll
            for (int m = 0; m < 4; ++m) {
                int f = f_lds[(rt * 16 + crow0 + m) * TT + t];
                tb[0][m] = tblv[f * 256 + dim0];
                tb[1][m] = tblv[f * 256 + dim0 + 16];
            }
            #pragma unroll
            for (int j = 0; j < 2; ++j)
                #pragma unroll
                for (int m = 0; m < 4; ++m) {
                    float zi = acc[rt][j][0][m] + tb[j][m].x;
                    float zj = acc[rt][j][1][m] + tb[j][m].y;
                    float zf = acc[rt][j][2][m] + tb[j][m].z;   // +1 folded
                    float zo = acc[rt][j][3][m] + tb[j][m].w;
                    float& cc = c[rt][j][m];
                    cc = cc * sigf(zf) + sigf(zi) * tanhfast(zj);
                    float hv = tanhfast(cc) * sigf(zo);
                    *(_Float16*)(nxt + swz(rt * 16 + crow0 + m, (dim0 + j * 16) * 2)) =
                        (_Float16)hv;
                }
        }
        __syncthreads();
    }

    // tail: h(79) sits in hb0 (t=79 odd -> nxt=hb0)
    #pragma unroll
    for (int p = 0; p < 2; ++p) {
        int i = p * 512 + tid, r = i >> 5, c16 = i & 31;
        *(half8*)(h1out + ((size_t)(TT - 1) * BB + brow + r) * HH + c16 * 8) =
            *(const half8*)(hb0 + swz(r, c16 * 16));
    }
}

// ---------------- za GEMM chunk (unchanged, proven) ----------------
__global__ __launch_bounds__(1024) void za_gemm_v3(
    const _Float16* __restrict__ h1, const _Float16* __restrict__ Wz,
    _Float16* __restrict__ za, int t0)
{
    const int tid = threadIdx.x, l = tid & 63, w = tid >> 6;
    const int chunk = l >> 4;
    const int dim = w * 16 + (l & 15);
    const size_t rloc = (size_t)blockIdx.x * 16;
    const size_t rglob = (size_t)t0 * BB + rloc;

    half8 a[8];
    #pragma unroll
    for (int kk = 0; kk < 8; ++kk)
        a[kk] = *(const half8*)(h1 + (rglob + (l & 15)) * HH + kk * 32 + chunk * 8);

    f32x4 acc[4];
    #pragma unroll
    for (int g = 0; g < 4; ++g) acc[g] = (f32x4){0.f, 0.f, 0.f, 0.f};
    const half8* wp = (const half8*)Wz + (size_t)w * 2048;
    half8 wbuf[2][4];
    #pragma unroll
    for (int g = 0; g < 4; ++g) wbuf[0][g] = wp[g * 64 + l];
    #pragma unroll
    for (int kk = 0; kk < 8; ++kk) {
        const int cur = kk & 1;
        if (kk < 7) {
            #pragma unroll
            for (int g = 0; g < 4; ++g)
                wbuf[cur ^ 1][g] = wp[(size_t)((kk + 1) * 4 + g) * 64 + l];
        }
        #pragma unroll
        for (int g = 0; g < 4; ++g)
            acc[g] = __builtin_amdgcn_mfma_f32_16x16x32_f16(
                a[kk], wbuf[cur][g], acc[g], 0, 0, 0);
    }
    #pragma unroll
    for (int m = 0; m < 4; ++m) {
        half4v v = { (_Float16)acc[0][m], (_Float16)acc[1][m],
                     (_Float16)acc[2][m], (_Float16)acc[3][m] };
        *(half4v*)(za + (rloc + chunk * 4 + m) * 1024 + dim * 4) = v;
    }
}

// ------------- phase 2 chunk: 64 blocks x 512 thr, M=32, K=256 ----------
__global__ __launch_bounds__(512, 2) void lstm2_v7(
    const _Float16* __restrict__ za, const _Float16* __restrict__ Wf,
    const float* __restrict__ b2, float* __restrict__ c_state,
    _Float16* __restrict__ h_state, const float* __restrict__ Wd,
    const float* __restrict__ bd, float* __restrict__ out,
    int t0, int tc, int last)
{
    __shared__ char hb0[16384], hb1[16384];
    const int tid = threadIdx.x, l = tid & 63, w = tid >> 6;
    const int row_a = l & 15, chunk = l >> 4;
    const int dim0 = w * 32 + (l & 15);
    const int crow0 = (l >> 4) * 4;
    const int brow = blockIdx.x * 32;

    float bv[2][4];
    #pragma unroll
    for (int j = 0; j < 2; ++j)
        #pragma unroll
        for (int g = 0; g < 4; ++g)
            bv[j][g] = b2[g * 256 + dim0 + j * 16] + (g == 2 ? 1.0f : 0.0f);

    float c[2][2][4];
    if (t0 == 0) {
        for (int i = tid; i < 4096; i += 512) ((float*)hb0)[i] = 0.f;
        #pragma unroll
        for (int rt = 0; rt < 2; ++rt)
            #pragma unroll
            for (int j = 0; j < 2; ++j)
                #pragma unroll
                for (int m = 0; m < 4; ++m) c[rt][j][m] = 0.f;
    } else {
        #pragma unroll
        for (int p = 0; p < 2; ++p) {
            int i = p * 512 + tid, r = i >> 5, c16 = i & 31;
            *(half8*)(hb0 + swz(r, c16 * 16)) =
                *(const half8*)(h_state + (size_t)(brow + r) * HH + c16 * 8);
        }
        #pragma unroll
        for (int rt = 0; rt < 2; ++rt)
            #pragma unroll
            for (int j = 0; j < 2; ++j)
                #pragma unroll
                for (int m = 0; m < 4; ++m)
                    c[rt][j][m] = c_state[(size_t)(brow + rt * 16 + crow0 + m) * HH
                                          + dim0 + j * 16];
    }
    const half8* wp = (const half8*)Wf + (size_t)w * 4096;
    half8 wbuf[2][8];
    #pragma unroll
    for (int jg = 0; jg < 8; ++jg) wbuf[0][jg] = wp[jg * 64 + l];
    __syncthreads();

    for (int tt = 0; tt < tc; ++tt) {
        char* cur = (tt & 1) ? hb1 : hb0;
        char* nxt = (tt & 1) ? hb0 : hb1;

        f32x4 acc[2][2][4];
        #pragma unroll
        for (int rt = 0; rt < 2; ++rt)
            #pragma unroll
            for (int j = 0; j < 2; ++j)
                #pragma unroll
                for (int g = 0; g < 4; ++g) acc[rt][j][g] = (f32x4){0.f, 0.f, 0.f, 0.f};

        #pragma unroll
        for (int kk = 0; kk < 8; ++kk) {
            const int cb = kk & 1;
            const int ng = (kk + 1) & 7;     // WRAP: kk=7 reloads group 0
            #pragma unroll
            for (int jg = 0; jg < 8; ++jg)
                wbuf[cb ^ 1][jg] = wp[(size_t)(ng * 8 + jg) * 64 + l];
            half8 a0 = *(const half8*)(cur + swz(row_a,      kk * 64 + chunk * 16));
            half8 a1 = *(const half8*)(cur + swz(row_a + 16, kk * 64 + chunk * 16));
            #pragma unroll
            for (int j = 0; j < 2; ++j)
                #pragma unroll
                for (int g = 0; g < 4; ++g) {
                    acc[0][j][g] = __builtin_amdgcn_mfma_f32_16x16x32_f16(
                        a0, wbuf[cb][j * 4 + g], acc[0][j][g], 0, 0, 0);
                    acc[1][j][g] = __builtin_amdgcn_mfma_f32_16x16x32_f16(
                        a1, wbuf[cb][j * 4 + g], acc[1][j][g], 0, 0, 0);
                }
        }

        #pragma unroll
        for (int rt = 0; rt < 2; ++rt) {
            half4v zv[2][4];
            #pragma unroll
            for (int j = 0; j < 2; ++j)
                #pragma unroll
                for (int m = 0; m < 4; ++m)
                    zv[j][m] = *(const half4v*)(za +
                        ((size_t)tt * BB + brow + rt * 16 + crow0 + m) * 1024
                        + (dim0 + j * 16) * 4);
            #pragma unroll
            for (int j = 0; j < 2; ++j)
                #pragma unroll
                for (int m = 0; m < 4; ++m) {
                    float zi = acc[rt][j][0][m] + bv[j][0] + (float)zv[j][m][0];
                    float zj = acc[rt][j][1][m] + bv[j][1] + (float)zv[j][m][1];
                    float zf = acc[rt][j][2][m] + bv[j][2] + (float)zv[j][m][2];
                    float zo = acc[rt][j][3][m] + bv[j][3] + (float)zv[j][m][3];
                    float& cc = c[rt][j][m];
                    cc = cc * sigf(zf) + sigf(zi) * tanhfast(zj);
                    float hv = tanhfast(cc) * sigf(zo);
                    *(_Float16*)(nxt + swz(rt * 16 + crow0 + m, (dim0 + j * 16) * 2)) =
                        (_Float16)hv;
                }
        }
        __syncthreads();
    }

    char* fin = (tc & 1) ? hb1 : hb0;
    if (!last) {
        #pragma unroll
        for (int rt = 0; rt < 2; ++rt)
            #pragma unroll
            for (int j = 0; j < 2; ++j)
                #pragma unroll
                for (int m = 0; m < 4; ++m)
                    c_state[(size_t)(brow + rt * 16 + crow0 + m) * HH + dim0 + j * 16]
                        = c[rt][j][m];
        #pragma unroll
        for (int p = 0; p < 2; ++p) {
            int i = p * 512 + tid, r = i >> 5, c16 = i & 31;
            *(half8*)(h_state + (size_t)(brow + r) * HH + c16 * 8) =
                *(const half8*)(fin + swz(r, c16 * 16));
        }
    } else {
        for (int idx = tid; idx < 32 * VV; idx += 512) {
            int r = idx / VV, v = idx - r * VV;
            float s = bd[v];
            for (int d = 0; d < HH; ++d)
                s = fmaf((float)*(const _Float16*)(fin + swz(r, d * 2)),
                         Wd[(size_t)d * VV + v], s);
            out[(size_t)(brow + r) * VV + v] = s;
        }
    }
}

// ---------------- fallback phase 2 (R6-proven, K=512) ----------------
__global__ __launch_bounds__(512, 2) void lstm2_old(
    const _Float16* __restrict__ h1, const _Float16* __restrict__ Wf,
    const float* __restrict__ b2, const float* __restrict__ Wd,
    const float* __restrict__ bd, float* __restrict__ out)
{
    __shared__ char h_lds[8192];
    const int tid = threadIdx.x, l = tid & 63, w = tid >> 6;
    const int brow = blockIdx.x * 16;
    const int row_a = l & 15, chunk = l >> 4;
    const int dim0 = w * 32 + (l & 15);

    for (int i = tid; i < 2048; i += 512) ((float*)h_lds)[i] = 0.f;
    float bv[2][4];
    #pragma unroll
    for (int j = 0; j < 2; ++j)
        #pragma unroll
        for (int g = 0; g < 4; ++g)
            bv[j][g] = b2[g * 256 + dim0 + j * 16] + (g == 2 ? 1.0f : 0.0f);
    float c[2][4] = {};
    __syncthreads();

    for (int t = 0; t < TT; ++t) {
        half8 a2[8];
        #pragma unroll
        for (int kk = 0; kk < 8; ++kk)
            a2[kk] = *(const half8*)(h_lds + swz(row_a, kk * 64 + chunk * 16));
        __syncthreads();

        half8 pa[8];
        const _Float16* hp = h1 + ((size_t)t * BB + brow + row_a) * HH + chunk * 8;
        #pragma unroll
        for (int kk = 0; kk < 8; ++kk) pa[kk] = *(const half8*)(hp + kk * 32);

        f32x4 acc[8];
        #pragma unroll
        for (int n = 0; n < 8; ++n) acc[n] = (f32x4){0.f, 0.f, 0.f, 0.f};
        const half8* wp = (const half8*)Wf + (size_t)w * 16 * 512;
        half8 wbuf[2][8];
        #pragma unroll
        for (int kk = 0; kk < 8; ++kk) wbuf[0][kk] = wp[(size_t)kk * 64 + l];
        #pragma unroll
        for (int gid = 0; gid < 16; ++gid) {
            const int cur = gid & 1;
            if (gid < 15) {
                #pragma unroll
                for (int kk = 0; kk < 8; ++kk)
                    wbuf[cur ^ 1][kk] = wp[(size_t)((gid + 1) * 8 + kk) * 64 + l];
            }
            const int s = gid >> 3, acci = gid & 7;
            #pragma unroll
            for (int kk = 0; kk < 8; ++kk)
                acc[acci] = __builtin_amdgcn_mfma_f32_16x16x32_f16(
                    s ? pa[kk] : a2[kk], wbuf[cur][kk], acc[acci], 0, 0, 0);
        }

        #pragma unroll
        for (int j = 0; j < 2; ++j) {
            const int D = dim0 + j * 16;
            #pragma unroll
            for (int m = 0; m < 4; ++m) {
                const int R = chunk * 4 + m;
                float zi = acc[j][m] + bv[j][0];
                float zj = acc[2 + j][m] + bv[j][1];
                float zf = acc[4 + j][m] + bv[j][2];
                float zo = acc[6 + j][m] + bv[j][3];
                c[j][m] = c[j][m] * sigf(zf) + sigf(zi) * tanhfast(zj);
                float hv = tanhfast(c[j][m]) * sigf(zo);
                *(_Float16*)(h_lds + swz(R, D * 2)) = (_Float16)hv;
            }
        }
        __syncthreads();
    }

    for (int idx = tid; idx < 16 * VV; idx += 512) {
        int r = idx / VV, v = idx - r * VV;
        float s = bd[v];
        for (int d = 0; d < HH; ++d) {
            float h2 = (float)*(const _Float16*)(h_lds + swz(r, d * 2));
            s = fmaf(h2, Wd[(size_t)d * VV + v], s);
        }
        out[(size_t)(brow + r) * VV + v] = s;
    }
}

extern "C" void kernel_launch(void* const* d_in, const int* in_sizes, int n_in,
                              void* d_out, int out_size, void* d_ws, size_t ws_size,
                              hipStream_t stream) {
    const int*   feats = (const int*)d_in[0];
    const float* emb   = (const float*)d_in[1];
    const float* W1    = (const float*)d_in[2];
    const float* b1    = (const float*)d_in[3];
    const float* W2    = (const float*)d_in[4];
    const float* b2    = (const float*)d_in[5];
    const float* Wd    = (const float*)d_in[6];
    const float* bd    = (const float*)d_in[7];
    float* out = (float*)d_out;

    char* ws = (char*)d_ws;
    float*    tbl     = (float*)ws;                       // 320 KiB
    _Float16* W1f     = (_Float16*)(ws + (512u << 10));   // 512 KiB
    _Float16* W2h     = (_Float16*)(ws + (1024u << 10));  // 512 KiB (1 MiB old)
    _Float16* W2z     = (_Float16*)(ws + (1536u << 10));  // 512 KiB
    float*    c_state = (float*)(ws + (2u << 20));        // 2 MiB
    _Float16* h_state = (_Float16*)(ws + (4u << 20));     // 1 MiB
    _Float16* h1      = (_Float16*)(ws + (8u << 20));     // 80 MiB
    _Float16* za      = (_Float16*)(ws + (88u << 20));    // TC * 4 MiB

    int TC = 0;
    if      (ws_size >= (160ull << 20)) TC = 16;
    else if (ws_size >= (128ull << 20)) TC = 8;
    else if (ws_size >= (108ull << 20)) TC = 4;

    prep_table<<<VV, 256, 0, stream>>>(emb, W1, b1, tbl);
    prep_w1_v6<<<128, 256, 0, stream>>>(W1, W1f);
    lstm1_v7<<<BB / 32, 512, 0, stream>>>(feats, tbl, W1f, h1);

    if (TC) {
        prep_w2h_v6<<<128, 256, 0, stream>>>(W2, W2h);
        prep_w2za_v2<<<128, 256, 0, stream>>>(W2, W2z);
        for (int t0 = 0; t0 < TT; t0 += TC) {
            za_gemm_v3<<<(BB * TC) / 16, 1024, 0, stream>>>(h1, W2z, za, t0);
            lstm2_v7<<<BB / 32, 512, 0, stream>>>(za, W2h, b2, c_state, h_state,
                                                  Wd, bd, out, t0, TC,
                                                  (t0 + TC == TT) ? 1 : 0);
        }
    } else {
        prep_w2_old<<<256, 256, 0, stream>>>(W2, W2h);
        lstm2_old<<<BB / 16, 512, 0, stream>>>(h1, W2h, b2, Wd, bd, out);
    }
}